// Round 1
// baseline (275.871 us; speedup 1.0000x reference)
//
#include <hip/hip_runtime.h>
#include <math.h>

// ---------------------------------------------------------------------------
// CrossAttention (Swin-style 3D window attention block) on gfx950.
// Round 1: correctness-first multi-kernel pipeline, bf16 MFMA for all matmuls,
// fp32 residual path. See journal in commit message.
//
// Pipeline:
//   prep:  proj_w/mw1/mw2 fp32->bf16 ; bias_table -> biasmat[8][128][128]
//   A: LN(q,k,v) + window-partition -> qw/kw/vw  (bf16, [512][128][256])
//   B: per (window,head) attention -> ao (bf16, window layout)
//   C: proj GEMM + bias + window-reverse + residual(v) -> x (fp32 spatial)
//   D: LN2(x) -> xln (bf16)
//   E: GEMM1 + GELU -> h1 (bf16, [65536][512])
//   F: GEMM2 + bias + residual(x) -> d_out (fp32)
//
// Workspace layout (bytes), overlays exploit dead buffers:
//   qw   [0,          33554432)
//   kw   [33554432,   67108864)
//   vw   [67108864,  100663296)
//   ao   [100663296, 134217728)
//   x    [0,          67108864)   (over qw+kw, dead after attn)
//   xln  [67108864,  100663296)   (over vw, dead after attn)
//   h1   [100663296, 167772160)   (over ao, dead after proj)
//   wp   [167772160, 167903232)
//   w1   [167903232, 168165376)
//   w2   [168165376, 168427520)
//   bias [168427520, 168951808)
// Total required ws: 168,951,808 B (~161 MiB).
// ---------------------------------------------------------------------------

typedef __attribute__((ext_vector_type(8))) short short8;
typedef __attribute__((ext_vector_type(4))) short shortx4;
typedef __attribute__((ext_vector_type(4))) float floatx4;

#define MFMA16(a, b, c) __builtin_amdgcn_mfma_f32_16x16x32_bf16((a), (b), (c), 0, 0, 0)

#define ATT_SCALE 0.17677669529663689f /* 32^-0.5 */

__device__ __forceinline__ short f2bf(float f) {
  unsigned u = __float_as_uint(f);
  u += 0x7fffu + ((u >> 16) & 1u);
  return (short)(u >> 16);
}

// ---------------------------------------------------------------------------
// prep kernels
// ---------------------------------------------------------------------------
__global__ void cvt_kernel(const float* __restrict__ src, short* __restrict__ dst, int n) {
  int i = blockIdx.x * 256 + threadIdx.x;
  if (i < n) dst[i] = f2bf(src[i]);
}

__global__ void bias_kernel(const float* __restrict__ table, float* __restrict__ biasm) {
  int idx = blockIdx.x * 256 + threadIdx.x;  // [0, 8*128*128)
  int h = idx >> 14;
  int n = (idx >> 7) & 127;
  int m = idx & 127;
  int t1 = n >> 6, h1 = (n >> 3) & 7, w1 = n & 7;
  int t2 = m >> 6, h2 = (m >> 3) & 7, w2 = m & 7;
  int ridx = (t1 - t2 + 1) * 225 + (h1 - h2 + 7) * 15 + (w1 - w2 + 7);
  biasm[idx] = table[ridx * 8 + h];
}

// ---------------------------------------------------------------------------
// Kernel A: LN over last dim (256) for q,k,v + window partition, fp32->bf16.
// One wave per token; grid (16384, 3), block 256.
// ---------------------------------------------------------------------------
__global__ __launch_bounds__(256) void ln_qkv_kernel(
    const float* __restrict__ q, const float* __restrict__ k, const float* __restrict__ v,
    const float* __restrict__ gq, const float* __restrict__ bq,
    const float* __restrict__ gk, const float* __restrict__ bk,
    const float* __restrict__ gv, const float* __restrict__ bv,
    short* __restrict__ qw, short* __restrict__ kw, short* __restrict__ vw) {
  const int wv = threadIdx.x >> 6, l = threadIdx.x & 63;
  const int tok = blockIdx.x * 4 + wv;  // 0..65535
  const int which = blockIdx.y;
  const float* src = (which == 0) ? q : ((which == 1) ? k : v);
  const float* gg  = (which == 0) ? gq : ((which == 1) ? gk : gv);
  const float* bb  = (which == 0) ? bq : ((which == 1) ? bk : bv);
  short* dst       = (which == 0) ? qw : ((which == 1) ? kw : vw);

  float4 xv = *(const float4*)(src + (size_t)tok * 256 + l * 4);
  float s1 = xv.x + xv.y + xv.z + xv.w;
  float s2 = xv.x * xv.x + xv.y * xv.y + xv.z * xv.z + xv.w * xv.w;
#pragma unroll
  for (int off = 1; off < 64; off <<= 1) {
    s1 += __shfl_xor(s1, off);
    s2 += __shfl_xor(s2, off);
  }
  float mean = s1 * (1.0f / 256.0f);
  float var = s2 * (1.0f / 256.0f) - mean * mean;
  float inv = rsqrtf(var + 1e-5f);

  // spatial -> (window, pos-in-window)
  int b_ = tok >> 15, rem = tok & 32767;
  int t = rem >> 12, hh = (rem >> 6) & 63, ww = rem & 63;
  int wi = ((b_ * 4 + (t >> 1)) * 8 + (hh >> 3)) * 8 + (ww >> 3);
  int n = ((t & 1) << 6) | ((hh & 7) << 3) | (ww & 7);

  float4 g4 = *(const float4*)(gg + l * 4);
  float4 b4 = *(const float4*)(bb + l * 4);
  shortx4 o;
  o[0] = f2bf((xv.x - mean) * inv * g4.x + b4.x);
  o[1] = f2bf((xv.y - mean) * inv * g4.y + b4.y);
  o[2] = f2bf((xv.z - mean) * inv * g4.z + b4.z);
  o[3] = f2bf((xv.w - mean) * inv * g4.w + b4.w);
  *(shortx4*)(dst + ((size_t)wi * 128 + n) * 256 + l * 4) = o;
}

// ---------------------------------------------------------------------------
// Kernel B: windowed attention, one block per (window wi, head h).
// 4 waves, each owns 32 rows of S. K=32 so QK^T is one MFMA per 16x16 tile.
// ---------------------------------------------------------------------------
__global__ __launch_bounds__(256) void attn_kernel(
    const short* __restrict__ qw, const short* __restrict__ kw, const short* __restrict__ vw,
    const float* __restrict__ biasm, short* __restrict__ ao) {
  __shared__ short Qs[128][40];
  __shared__ short Ks[128][40];
  __shared__ short Vt[32][136];
  __shared__ short Ps[128][136];

  const int wi = blockIdx.x, h = blockIdx.y;
  const int tid = threadIdx.x;
  const size_t base = ((size_t)wi * 128) * 256 + h * 32;

  // stage Q,K [128][32] -> padded LDS
#pragma unroll
  for (int i = 0; i < 2; ++i) {
    int ch = tid + 256 * i;  // 0..511
    int m = ch >> 2, c = ch & 3;
    *(short8*)&Qs[m][c * 8] = *(const short8*)(qw + base + (size_t)m * 256 + c * 8);
    *(short8*)&Ks[m][c * 8] = *(const short8*)(kw + base + (size_t)m * 256 + c * 8);
  }
  // stage V transposed: Vt[d][m]
#pragma unroll
  for (int i = 0; i < 16; ++i) {
    int idx = tid + 256 * i;  // 0..4095
    int m = idx >> 5, d = idx & 31;
    Vt[d][m] = vw[base + (size_t)m * 256 + d];
  }
  __syncthreads();

  const int wvv = tid >> 6, l = tid & 63, lr = l & 15, g = l >> 4;
  const floatx4 zf = {0.f, 0.f, 0.f, 0.f};

  short8 aq0 = *(const short8*)&Qs[32 * wvv + lr][g * 8];
  short8 aq1 = *(const short8*)&Qs[32 * wvv + 16 + lr][g * 8];

  floatx4 s[2][8];
#pragma unroll
  for (int c = 0; c < 8; ++c) {
    short8 bk = *(const short8*)&Ks[16 * c + lr][g * 8];
    s[0][c] = MFMA16(aq0, bk, zf);
    s[1][c] = MFMA16(aq1, bk, zf);
  }

  const float* bp = biasm + (size_t)h * 128 * 128;
#pragma unroll
  for (int r = 0; r < 2; ++r) {
#pragma unroll
    for (int j = 0; j < 4; ++j) {
      int n = 32 * wvv + 16 * r + 4 * g + j;
      float mx = -1e30f;
#pragma unroll
      for (int c = 0; c < 8; ++c) {
        float val = s[r][c][j] * ATT_SCALE + bp[n * 128 + 16 * c + lr];
        s[r][c][j] = val;
        mx = fmaxf(mx, val);
      }
#pragma unroll
      for (int off = 1; off < 16; off <<= 1) mx = fmaxf(mx, __shfl_xor(mx, off));
      float sum = 0.f;
#pragma unroll
      for (int c = 0; c < 8; ++c) {
        float e = __expf(s[r][c][j] - mx);
        s[r][c][j] = e;
        sum += e;
      }
#pragma unroll
      for (int off = 1; off < 16; off <<= 1) sum += __shfl_xor(sum, off);
      float invs = 1.0f / sum;
#pragma unroll
      for (int c = 0; c < 8; ++c) Ps[n][16 * c + lr] = f2bf(s[r][c][j] * invs);
    }
  }
  // No barrier needed: each wave reads only its own 32 P-rows below.

  floatx4 o00 = zf, o01 = zf, o10 = zf, o11 = zf;
#pragma unroll
  for (int ks = 0; ks < 4; ++ks) {
    short8 pa0 = *(const short8*)&Ps[32 * wvv + lr][ks * 32 + g * 8];
    short8 pa1 = *(const short8*)&Ps[32 * wvv + 16 + lr][ks * 32 + g * 8];
    short8 vb0 = *(const short8*)&Vt[lr][ks * 32 + g * 8];
    short8 vb1 = *(const short8*)&Vt[16 + lr][ks * 32 + g * 8];
    o00 = MFMA16(pa0, vb0, o00);
    o01 = MFMA16(pa0, vb1, o01);
    o10 = MFMA16(pa1, vb0, o10);
    o11 = MFMA16(pa1, vb1, o11);
  }
#pragma unroll
  for (int j = 0; j < 4; ++j) {
    int n0 = 32 * wvv + 4 * g + j;
    int n1 = n0 + 16;
    size_t rb0 = ((size_t)wi * 128 + n0) * 256 + h * 32;
    size_t rb1 = ((size_t)wi * 128 + n1) * 256 + h * 32;
    ao[rb0 + lr] = f2bf(o00[j]);
    ao[rb0 + 16 + lr] = f2bf(o01[j]);
    ao[rb1 + lr] = f2bf(o10[j]);
    ao[rb1 + 16 + lr] = f2bf(o11[j]);
  }
}

// ---------------------------------------------------------------------------
// GEMM core: C[128 x 256] += A[128 x K] * W[256 x K]^T  (both row-major, bf16)
// 512 threads = 8 waves; wave w owns rows 16w..16w+15 x all 256 cols.
// ---------------------------------------------------------------------------
template <int K>
__device__ __forceinline__ void gemm_acc(const short* __restrict__ A,
                                         const short* __restrict__ W,
                                         floatx4 (&acc)[16]) {
  __shared__ short As[128][40];
  __shared__ short Ws[256][40];
  const int tid = threadIdx.x;
  const int wvv = tid >> 6, l = tid & 63, lr = l & 15, g = l >> 4;
  const floatx4 zf = {0.f, 0.f, 0.f, 0.f};
#pragma unroll
  for (int i = 0; i < 16; ++i) acc[i] = zf;
  const int srow = tid >> 2, sc = tid & 3;
  for (int k0 = 0; k0 < K; k0 += 32) {
    short8 va = *(const short8*)(A + (size_t)srow * K + k0 + sc * 8);
    short8 w0 = *(const short8*)(W + (size_t)srow * K + k0 + sc * 8);
    short8 w1 = *(const short8*)(W + (size_t)(srow + 128) * K + k0 + sc * 8);
    __syncthreads();
    *(short8*)&As[srow][sc * 8] = va;
    *(short8*)&Ws[srow][sc * 8] = w0;
    *(short8*)&Ws[srow + 128][sc * 8] = w1;
    __syncthreads();
    short8 a = *(const short8*)&As[16 * wvv + lr][g * 8];
#pragma unroll
    for (int ct = 0; ct < 16; ++ct) {
      short8 b = *(const short8*)&Ws[ct * 16 + lr][g * 8];
      acc[ct] = MFMA16(a, b, acc[ct]);
    }
  }
}

// Kernel C: projection + bias + window-reverse + residual(v) -> x (fp32 spatial)
__global__ __launch_bounds__(512) void proj_kernel(
    const short* __restrict__ ao, const short* __restrict__ wp,
    const float* __restrict__ proj_b, const float* __restrict__ vin,
    float* __restrict__ x) {
  floatx4 acc[16];
  gemm_acc<256>(ao + (size_t)blockIdx.x * 128 * 256, wp, acc);
  const int tid = threadIdx.x, wvv = tid >> 6, l = tid & 63, lr = l & 15, g = l >> 4;
#pragma unroll
  for (int ct = 0; ct < 16; ++ct) {
    int col = ct * 16 + lr;
    float pb = proj_b[col];
#pragma unroll
    for (int j = 0; j < 4; ++j) {
      int mrow = blockIdx.x * 128 + 16 * wvv + 4 * g + j;  // window-ordered token
      int wi = mrow >> 7, n = mrow & 127;
      int wb = wi & 7, hb = (wi >> 3) & 7, tt = (wi >> 6) & 3, b_ = wi >> 8;
      int t = tt * 2 + (n >> 6), hh = hb * 8 + ((n >> 3) & 7), ww = wb * 8 + (n & 7);
      size_t sidx = (((size_t)b_ * 8 + t) * 64 + hh) * 64 + ww;
      x[sidx * 256 + col] = acc[ct][j] + pb + vin[sidx * 256 + col];
    }
  }
}

// Kernel D: LN2 over x (fp32 spatial) -> xln (bf16 spatial)
__global__ __launch_bounds__(256) void ln2_kernel(
    const float* __restrict__ x, const float* __restrict__ g2, const float* __restrict__ b2,
    short* __restrict__ xln) {
  const int wvv = threadIdx.x >> 6, l = threadIdx.x & 63;
  const size_t tok = (size_t)blockIdx.x * 4 + wvv;
  float4 xv = *(const float4*)(x + tok * 256 + l * 4);
  float s1 = xv.x + xv.y + xv.z + xv.w;
  float s2 = xv.x * xv.x + xv.y * xv.y + xv.z * xv.z + xv.w * xv.w;
#pragma unroll
  for (int off = 1; off < 64; off <<= 1) {
    s1 += __shfl_xor(s1, off);
    s2 += __shfl_xor(s2, off);
  }
  float mean = s1 * (1.0f / 256.0f);
  float var = s2 * (1.0f / 256.0f) - mean * mean;
  float inv = rsqrtf(var + 1e-5f);
  float4 g4 = *(const float4*)(g2 + l * 4);
  float4 b4 = *(const float4*)(b2 + l * 4);
  shortx4 o;
  o[0] = f2bf((xv.x - mean) * inv * g4.x + b4.x);
  o[1] = f2bf((xv.y - mean) * inv * g4.y + b4.y);
  o[2] = f2bf((xv.z - mean) * inv * g4.z + b4.z);
  o[3] = f2bf((xv.w - mean) * inv * g4.w + b4.w);
  *(shortx4*)(xln + tok * 256 + l * 4) = o;
}

// Kernel E: MLP layer 1 + GELU -> h1 bf16 [65536][512]; grid (512, 2)
__global__ __launch_bounds__(512) void mlp1_kernel(
    const short* __restrict__ xln, const short* __restrict__ w1,
    const float* __restrict__ mb1, short* __restrict__ h1) {
  floatx4 acc[16];
  gemm_acc<256>(xln + (size_t)blockIdx.x * 128 * 256, w1 + (size_t)blockIdx.y * 256 * 256, acc);
  const int tid = threadIdx.x, wvv = tid >> 6, l = tid & 63, lr = l & 15, g = l >> 4;
  const int colbase = blockIdx.y * 256;
#pragma unroll
  for (int ct = 0; ct < 16; ++ct) {
    int col = ct * 16 + lr;
    float bias = mb1[colbase + col];
#pragma unroll
    for (int j = 0; j < 4; ++j) {
      int mrow = blockIdx.x * 128 + 16 * wvv + 4 * g + j;
      float val = acc[ct][j] + bias;
      float ge = 0.5f * val * (1.0f + erff(val * 0.70710678118654752f));
      h1[(size_t)mrow * 512 + colbase + col] = f2bf(ge);
    }
  }
}

// Kernel F: MLP layer 2 + bias + residual(x) -> d_out fp32
__global__ __launch_bounds__(512) void mlp2_kernel(
    const short* __restrict__ h1, const short* __restrict__ w2,
    const float* __restrict__ mb2, const float* __restrict__ x,
    float* __restrict__ out) {
  floatx4 acc[16];
  gemm_acc<512>(h1 + (size_t)blockIdx.x * 128 * 512, w2, acc);
  const int tid = threadIdx.x, wvv = tid >> 6, l = tid & 63, lr = l & 15, g = l >> 4;
#pragma unroll
  for (int ct = 0; ct < 16; ++ct) {
    int col = ct * 16 + lr;
    float bias = mb2[col];
#pragma unroll
    for (int j = 0; j < 4; ++j) {
      int mrow = blockIdx.x * 128 + 16 * wvv + 4 * g + j;
      out[(size_t)mrow * 256 + col] = x[(size_t)mrow * 256 + col] + acc[ct][j] + bias;
    }
  }
}

// ---------------------------------------------------------------------------
extern "C" void kernel_launch(void* const* d_in, const int* in_sizes, int n_in,
                              void* d_out, int out_size, void* d_ws, size_t ws_size,
                              hipStream_t stream) {
  const float* q = (const float*)d_in[0];
  const float* k = (const float*)d_in[1];
  const float* v = (const float*)d_in[2];
  const float* gq = (const float*)d_in[3];
  const float* bq = (const float*)d_in[4];
  const float* gk = (const float*)d_in[5];
  const float* bk = (const float*)d_in[6];
  const float* gv = (const float*)d_in[7];
  const float* bv = (const float*)d_in[8];
  const float* bias_table = (const float*)d_in[9];
  const float* proj_w = (const float*)d_in[10];
  const float* proj_b = (const float*)d_in[11];
  const float* g2 = (const float*)d_in[12];
  const float* b2 = (const float*)d_in[13];
  const float* mw1 = (const float*)d_in[14];
  const float* mb1 = (const float*)d_in[15];
  const float* mw2 = (const float*)d_in[16];
  const float* mb2 = (const float*)d_in[17];

  char* ws = (char*)d_ws;
  short* qw = (short*)(ws + 0);
  short* kw = (short*)(ws + 33554432);
  short* vw = (short*)(ws + 67108864);
  short* ao = (short*)(ws + 100663296);
  float* x = (float*)(ws + 0);           // overlays qw+kw (dead after attn)
  short* xln = (short*)(ws + 67108864);  // overlays vw (dead after attn)
  short* h1 = (short*)(ws + 100663296);  // overlays ao (dead after proj)
  short* wp = (short*)(ws + 167772160);
  short* w1 = (short*)(ws + 167903232);
  short* w2 = (short*)(ws + 168165376);
  float* biasm = (float*)(ws + 168427520);
  // total ws requirement: 168,951,808 bytes

  // prep
  cvt_kernel<<<256, 256, 0, stream>>>(proj_w, wp, 65536);
  cvt_kernel<<<512, 256, 0, stream>>>(mw1, w1, 131072);
  cvt_kernel<<<512, 256, 0, stream>>>(mw2, w2, 131072);
  bias_kernel<<<512, 256, 0, stream>>>(bias_table, biasm);

  // A: LN + window partition (q,k,v)
  ln_qkv_kernel<<<dim3(16384, 3), 256, 0, stream>>>(q, k, v, gq, bq, gk, bk, gv, bv, qw, kw, vw);

  // B: attention per (window, head)
  attn_kernel<<<dim3(512, 8), 256, 0, stream>>>(qw, kw, vw, biasm, ao);

  // C: projection + residual + window reverse
  proj_kernel<<<512, 512, 0, stream>>>(ao, wp, proj_b, v, x);

  // D: LN2
  ln2_kernel<<<16384, 256, 0, stream>>>(x, g2, b2, xln);

  // E: MLP1 + GELU
  mlp1_kernel<<<dim3(512, 2), 512, 0, stream>>>(xln, w1, mb1, h1);

  // F: MLP2 + residual -> out
  mlp2_kernel<<<512, 512, 0, stream>>>(h1, w2, mb2, x, (float*)d_out);
}

// Round 2
// 249.494 us; speedup vs baseline: 1.1057x; 1.1057x over previous
//
#include <hip/hip_runtime.h>
#include <math.h>

// ---------------------------------------------------------------------------
// Round 2: fused/leaner pipeline.
//   prep:  proj_w/mw1/mw2 fp32->bf16 ; bias_table -> biasPb[h][n][lr][8] bf16
//   S: per-token LN stats (mean, rsqrt) for q,k,v
//   B: attention per (window,head): stages fp32 q/k/v + LN on the fly,
//      40KB LDS (4 blocks/CU), XOR-swizzled Ps/Vt, bf16 b128 bias loads -> ao
//   C: proj GEMM (global_load_lds+swizzle) + bias + residual(v) + fused LN2
//      -> x (fp32 spatial) + xln (bf16 spatial)
//   E: MLP1 GEMM + GELU -> h1
//   F: MLP2 GEMM + bias + residual(x) -> out
//
// Workspace layout (bytes):
//   sq/sk/sv  [0, 1572864)              (dead after attn; proj overwrites)
//   x         [0, 67108864)
//   ao        [67108864, 100663296)     (dead after proj)
//   h1        [67108864, 134217728)     (overlays ao, written by mlp1)
//   xln       [134217728, 167772160)
//   wp        [167772160, 167903232)
//   w1        [167903232, 168165376)
//   w2        [168165376, 168427520)
//   biasPb    [168427520, 168689664)
// Total 168,689,664 B <= round-1's 168,951,808 B (known-good ws_size).
// ---------------------------------------------------------------------------

typedef __attribute__((ext_vector_type(8))) short short8;
typedef __attribute__((ext_vector_type(4))) short shortx4;
typedef __attribute__((ext_vector_type(4))) float floatx4;

#define MFMA16(a, b, c) __builtin_amdgcn_mfma_f32_16x16x32_bf16((a), (b), (c), 0, 0, 0)
#define ATT_SCALE 0.17677669529663689f /* 32^-0.5 */

__device__ __forceinline__ short f2bf(float f) {
  unsigned u = __float_as_uint(f);
  u += 0x7fffu + ((u >> 16) & 1u);
  return (short)(u >> 16);
}
__device__ __forceinline__ float bf2f(short s) {
  return __uint_as_float(((unsigned)(unsigned short)s) << 16);
}
// async global->LDS, 16B per lane. dest must be wave-uniform base (+lane*16 by HW).
__device__ __forceinline__ void gl2lds(const short* g, short* l) {
  __builtin_amdgcn_global_load_lds((const __attribute__((address_space(1))) void*)(g),
                                   (__attribute__((address_space(3))) void*)(l), 16, 0, 0);
}

// ---------------------------------------------------------------------------
// prep kernels
// ---------------------------------------------------------------------------
__global__ void cvt_kernel(const float* __restrict__ src, short* __restrict__ dst, int n) {
  int i = blockIdx.x * 256 + threadIdx.x;
  if (i < n) dst[i] = f2bf(src[i]);
}

// biasPb[h][n][lr][c] = bf16( table[relidx(n, m=16c+lr)*8 + h] )
__global__ void biasprep_kernel(const float* __restrict__ table, short* __restrict__ biasPb) {
  int idx = blockIdx.x * 256 + threadIdx.x;  // [0, 131072)
  int h = idx >> 14;
  int n = (idx >> 7) & 127;
  int lr = (idx >> 3) & 15;
  int c = idx & 7;
  int m = 16 * c + lr;
  int t1 = n >> 6, h1 = (n >> 3) & 7, w1 = n & 7;
  int t2 = m >> 6, h2 = (m >> 3) & 7, w2 = m & 7;
  int ridx = (t1 - t2 + 1) * 225 + (h1 - h2 + 7) * 15 + (w1 - w2 + 7);
  biasPb[idx] = f2bf(table[ridx * 8 + h]);
}

// ---------------------------------------------------------------------------
// Kernel S: per-token LN stats {mean, rsqrt(var+eps)} for q,k,v. One wave/token.
// ---------------------------------------------------------------------------
__global__ __launch_bounds__(256) void stats_kernel(
    const float* __restrict__ q, const float* __restrict__ k, const float* __restrict__ v,
    float2* __restrict__ sq, float2* __restrict__ sk, float2* __restrict__ sv) {
  const int wv = threadIdx.x >> 6, l = threadIdx.x & 63;
  const int tok = blockIdx.x * 4 + wv;
  const int which = blockIdx.y;
  const float* src = (which == 0) ? q : ((which == 1) ? k : v);
  float2* dst = (which == 0) ? sq : ((which == 1) ? sk : sv);
  float4 xv = *(const float4*)(src + (size_t)tok * 256 + l * 4);
  float s1 = xv.x + xv.y + xv.z + xv.w;
  float s2 = xv.x * xv.x + xv.y * xv.y + xv.z * xv.z + xv.w * xv.w;
#pragma unroll
  for (int off = 1; off < 64; off <<= 1) {
    s1 += __shfl_xor(s1, off);
    s2 += __shfl_xor(s2, off);
  }
  float mean = s1 * (1.0f / 256.0f);
  float var = s2 * (1.0f / 256.0f) - mean * mean;
  if (l == 0) dst[tok] = make_float2(mean, rsqrtf(var + 1e-5f));
}

// ---------------------------------------------------------------------------
// Kernel B: windowed attention, one block per (window, head), 4 waves.
// LDS = union(Qs+Ks, Ps) + Vt = 40960 B -> 4 blocks/CU.
// ---------------------------------------------------------------------------
__global__ __launch_bounds__(256, 4) void attn_kernel(
    const float* __restrict__ q, const float* __restrict__ k, const float* __restrict__ v,
    const float* __restrict__ gq, const float* __restrict__ bq,
    const float* __restrict__ gk, const float* __restrict__ bk,
    const float* __restrict__ gv, const float* __restrict__ bv,
    const float2* __restrict__ sq, const float2* __restrict__ sk, const float2* __restrict__ sv,
    const short* __restrict__ biasPb, short* __restrict__ ao) {
  __shared__ union SU {
    struct { short Qs[128][40]; short Ks[128][40]; } qk;
    short Ps[128 * 128];  // XOR-swizzled (unit16B ^ (row&7))
  } su;
  __shared__ short Vt[32 * 128];  // V^T, XOR-swizzled

  const int wi = blockIdx.x, h = blockIdx.y, tid = threadIdx.x;
  const int b_ = wi >> 8, tt = (wi >> 6) & 3, hb = (wi >> 3) & 7, wb = wi & 7;
  const int uu = tid & 7;

  // hoisted gamma/beta slices (depend only on uu)
  const float4 gq4 = *(const float4*)(gq + h * 32 + uu * 4);
  const float4 bq4 = *(const float4*)(bq + h * 32 + uu * 4);
  const float4 gk4 = *(const float4*)(gk + h * 32 + uu * 4);
  const float4 bk4 = *(const float4*)(bk + h * 32 + uu * 4);
  const float4 gv4 = *(const float4*)(gv + h * 32 + uu * 4);
  const float4 bv4 = *(const float4*)(bv + h * 32 + uu * 4);

#pragma unroll
  for (int p = 0; p < 4; ++p) {
    int row = p * 32 + (tid >> 3);
    int t = row >> 6, h2 = (row >> 3) & 7, w2 = row & 7;
    size_t sidx = (((size_t)(b_ * 8 + tt * 2 + t)) * 64 + hb * 8 + h2) * 64 + wb * 8 + w2;
    size_t gbase = sidx * 256 + h * 32 + uu * 4;
    // Q
    {
      float4 xv = *(const float4*)(q + gbase);
      float2 st = sq[sidx];
      shortx4 o;
      o[0] = f2bf((xv.x - st.x) * st.y * gq4.x + bq4.x);
      o[1] = f2bf((xv.y - st.x) * st.y * gq4.y + bq4.y);
      o[2] = f2bf((xv.z - st.x) * st.y * gq4.z + bq4.z);
      o[3] = f2bf((xv.w - st.x) * st.y * gq4.w + bq4.w);
      *(shortx4*)&su.qk.Qs[row][uu * 4] = o;
    }
    // K
    {
      float4 xv = *(const float4*)(k + gbase);
      float2 st = sk[sidx];
      shortx4 o;
      o[0] = f2bf((xv.x - st.x) * st.y * gk4.x + bk4.x);
      o[1] = f2bf((xv.y - st.x) * st.y * gk4.y + bk4.y);
      o[2] = f2bf((xv.z - st.x) * st.y * gk4.z + bk4.z);
      o[3] = f2bf((xv.w - st.x) * st.y * gk4.w + bk4.w);
      *(shortx4*)&su.qk.Ks[row][uu * 4] = o;
    }
    // V -> transposed+swizzled LDS
    {
      float4 xv = *(const float4*)(v + gbase);
      float2 st = sv[sidx];
      float vals[4] = {(xv.x - st.x) * st.y * gv4.x + bv4.x,
                       (xv.y - st.x) * st.y * gv4.y + bv4.y,
                       (xv.z - st.x) * st.y * gv4.z + bv4.z,
                       (xv.w - st.x) * st.y * gv4.w + bv4.w};
#pragma unroll
      for (int e = 0; e < 4; ++e) {
        int d = uu * 4 + e;
        Vt[d * 128 + (((row >> 3) ^ (d & 7)) << 3) + (row & 7)] = f2bf(vals[e]);
      }
    }
  }
  __syncthreads();

  const int wvv = tid >> 6, l = tid & 63, lr = l & 15, g = l >> 4;
  const floatx4 zf = {0.f, 0.f, 0.f, 0.f};

  short8 aq0 = *(const short8*)&su.qk.Qs[32 * wvv + lr][g * 8];
  short8 aq1 = *(const short8*)&su.qk.Qs[32 * wvv + 16 + lr][g * 8];

  floatx4 s[2][8];
#pragma unroll
  for (int c = 0; c < 8; ++c) {
    short8 bk8 = *(const short8*)&su.qk.Ks[16 * c + lr][g * 8];
    s[0][c] = MFMA16(aq0, bk8, zf);
    s[1][c] = MFMA16(aq1, bk8, zf);
  }
  __syncthreads();  // Qs/Ks dead -> Ps region reusable

  const int lr7 = lr & 7;
#pragma unroll
  for (int r = 0; r < 2; ++r) {
#pragma unroll
    for (int j = 0; j < 4; ++j) {
      int n = 32 * wvv + 16 * r + 4 * g + j;
      short8 bv8 = *(const short8*)(biasPb + ((size_t)(h * 128 + n) * 16 + lr) * 8);
      float mx = -1e30f;
#pragma unroll
      for (int c = 0; c < 8; ++c) {
        float val = s[r][c][j] * ATT_SCALE + bf2f(bv8[c]);
        s[r][c][j] = val;
        mx = fmaxf(mx, val);
      }
#pragma unroll
      for (int off = 1; off < 16; off <<= 1) mx = fmaxf(mx, __shfl_xor(mx, off));
      float sum = 0.f;
#pragma unroll
      for (int c = 0; c < 8; ++c) {
        float e = __expf(s[r][c][j] - mx);
        s[r][c][j] = e;
        sum += e;
      }
#pragma unroll
      for (int off = 1; off < 16; off <<= 1) sum += __shfl_xor(sum, off);
      float invs = 1.0f / sum;
      int n7 = n & 7;
#pragma unroll
      for (int c = 0; c < 8; ++c) {
        int col = 16 * c + lr;
        su.Ps[n * 128 + (((col >> 3) ^ n7) << 3) + (col & 7)] = f2bf(s[r][c][j] * invs);
      }
    }
  }
  // each wave reads only its own 32 P rows below -> no barrier

  floatx4 o00 = zf, o01 = zf, o10 = zf, o11 = zf;
  const int ra0 = 32 * wvv + lr, ra1 = ra0 + 16;
#pragma unroll
  for (int ks = 0; ks < 4; ++ks) {
    int ulog = ks * 4 + g;
    short8 pa0 = *(const short8*)&su.Ps[ra0 * 128 + ((ulog ^ (ra0 & 7)) << 3)];
    short8 pa1 = *(const short8*)&su.Ps[ra1 * 128 + ((ulog ^ (ra1 & 7)) << 3)];
    short8 vb0 = *(const short8*)&Vt[lr * 128 + ((ulog ^ lr7) << 3)];
    short8 vb1 = *(const short8*)&Vt[(16 + lr) * 128 + ((ulog ^ lr7) << 3)];
    o00 = MFMA16(pa0, vb0, o00);
    o01 = MFMA16(pa0, vb1, o01);
    o10 = MFMA16(pa1, vb0, o10);
    o11 = MFMA16(pa1, vb1, o11);
  }
#pragma unroll
  for (int j = 0; j < 4; ++j) {
    int n0 = 32 * wvv + 4 * g + j;
    int n1 = n0 + 16;
    size_t rb0 = ((size_t)wi * 128 + n0) * 256 + h * 32;
    size_t rb1 = ((size_t)wi * 128 + n1) * 256 + h * 32;
    ao[rb0 + lr] = f2bf(o00[j]);
    ao[rb0 + 16 + lr] = f2bf(o01[j]);
    ao[rb1 + lr] = f2bf(o10[j]);
    ao[rb1 + 16 + lr] = f2bf(o11[j]);
  }
}

// ---------------------------------------------------------------------------
// GEMM core v2: C[128 x 256] = A[128 x K] * W[256 x K]^T, bf16, BK=64,
// global_load_lds(16B) with pre-swizzled source + XOR-swizzled ds_read.
// 512 threads = 8 waves; wave w owns rows 16w..16w+15, all 256 cols.
// ---------------------------------------------------------------------------
template <int K>
__device__ __forceinline__ void gemm_core(const short* __restrict__ A,
                                          const short* __restrict__ W,
                                          floatx4 (&acc)[16]) {
  __shared__ short As[128 * 64];  // 16 KB, 16 chunks of 1KB (8 rows x 8 units)
  __shared__ short Ws[256 * 64];  // 32 KB, 32 chunks
  const int tid = threadIdx.x;
  const int w = tid >> 6, l = tid & 63, lr = l & 15, g = l >> 4;
  const floatx4 zf = {0.f, 0.f, 0.f, 0.f};
#pragma unroll
  for (int i = 0; i < 16; ++i) acc[i] = zf;

  // staging lane params: row_in_chunk li = l>>3, unit u = l&7 ; swizzle u^li
  const int li = l >> 3, u = l & 7;
  const int swz = ((u ^ li) << 3);  // element offset within 64-elem row slice
  const size_t aoff0 = (size_t)(w * 8 + li) * K + swz;
  const size_t aoff1 = (size_t)((w + 8) * 8 + li) * K + swz;
  const size_t woff0 = (size_t)(w * 8 + li) * K + swz;
  const size_t woff1 = (size_t)((w + 8) * 8 + li) * K + swz;
  const size_t woff2 = (size_t)((w + 16) * 8 + li) * K + swz;
  const size_t woff3 = (size_t)((w + 24) * 8 + li) * K + swz;
  short* dA0 = As + w * 512;
  short* dA1 = As + (w + 8) * 512;
  short* dW0 = Ws + w * 512;
  short* dW1 = Ws + (w + 8) * 512;
  short* dW2 = Ws + (w + 16) * 512;
  short* dW3 = Ws + (w + 24) * 512;

  const int ra = 16 * w + lr;
  const int s0 = ((g ^ (lr & 7)) << 3);
  const int s1 = (((4 + g) ^ (lr & 7)) << 3);

  for (int k0 = 0; k0 < K; k0 += 64) {
    if (k0) __syncthreads();
    gl2lds(A + aoff0 + k0, dA0);
    gl2lds(A + aoff1 + k0, dA1);
    gl2lds(W + woff0 + k0, dW0);
    gl2lds(W + woff1 + k0, dW1);
    gl2lds(W + woff2 + k0, dW2);
    gl2lds(W + woff3 + k0, dW3);
    __syncthreads();  // drains vmcnt -> staged data visible
    short8 a0 = *(const short8*)&As[ra * 64 + s0];
    short8 a1 = *(const short8*)&As[ra * 64 + s1];
#pragma unroll
    for (int ct = 0; ct < 16; ++ct) {
      int rb = ct * 16 + lr;
      short8 b0 = *(const short8*)&Ws[rb * 64 + s0];
      acc[ct] = MFMA16(a0, b0, acc[ct]);
      short8 b1 = *(const short8*)&Ws[rb * 64 + s1];
      acc[ct] = MFMA16(a1, b1, acc[ct]);
    }
  }
}

// Kernel C: proj GEMM + bias + window-reverse + residual(v) + fused LN2
__global__ __launch_bounds__(512, 4) void proj_kernel(
    const short* __restrict__ ao, const short* __restrict__ wp,
    const float* __restrict__ proj_b, const float* __restrict__ vin,
    const float* __restrict__ g2, const float* __restrict__ b2,
    float* __restrict__ x, short* __restrict__ xln) {
  floatx4 acc[16];
  gemm_core<256>(ao + (size_t)blockIdx.x * 128 * 256, wp, acc);
  const int tid = threadIdx.x, w = tid >> 6, l = tid & 63, lr = l & 15, g = l >> 4;
#pragma unroll
  for (int j = 0; j < 4; ++j) {
    int mrow = blockIdx.x * 128 + 16 * w + 4 * g + j;  // window-ordered token
    int wi = mrow >> 7, n = mrow & 127;
    int wb = wi & 7, hb = (wi >> 3) & 7, tt = (wi >> 6) & 3, b_ = wi >> 8;
    int t = tt * 2 + (n >> 6), hh = hb * 8 + ((n >> 3) & 7), ww = wb * 8 + (n & 7);
    size_t sidx = (((size_t)b_ * 8 + t) * 64 + hh) * 64 + ww;
    float xr[16];
    float ss1 = 0.f, ss2 = 0.f;
#pragma unroll
    for (int ct = 0; ct < 16; ++ct) {
      int col = ct * 16 + lr;
      float val = acc[ct][j] + proj_b[col] + vin[sidx * 256 + col];
      xr[ct] = val;
      ss1 += val;
      ss2 += val * val;
    }
#pragma unroll
    for (int off = 1; off < 16; off <<= 1) {
      ss1 += __shfl_xor(ss1, off);
      ss2 += __shfl_xor(ss2, off);
    }
    float mean = ss1 * (1.0f / 256.0f);
    float var = ss2 * (1.0f / 256.0f) - mean * mean;
    float inv = rsqrtf(var + 1e-5f);
#pragma unroll
    for (int ct = 0; ct < 16; ++ct) {
      int col = ct * 16 + lr;
      x[sidx * 256 + col] = xr[ct];
      xln[sidx * 256 + col] = f2bf((xr[ct] - mean) * inv * g2[col] + b2[col]);
    }
  }
}

// Kernel E: MLP1 + GELU -> h1 bf16 [65536][512]; grid (512, 2)
__global__ __launch_bounds__(512, 4) void mlp1_kernel(
    const short* __restrict__ xln, const short* __restrict__ w1,
    const float* __restrict__ mb1, short* __restrict__ h1) {
  floatx4 acc[16];
  gemm_core<256>(xln + (size_t)blockIdx.x * 128 * 256, w1 + (size_t)blockIdx.y * 256 * 256, acc);
  const int tid = threadIdx.x, w = tid >> 6, l = tid & 63, lr = l & 15, g = l >> 4;
  const int colbase = blockIdx.y * 256;
#pragma unroll
  for (int ct = 0; ct < 16; ++ct) {
    int col = ct * 16 + lr;
    float bias = mb1[colbase + col];
#pragma unroll
    for (int j = 0; j < 4; ++j) {
      int mrow = blockIdx.x * 128 + 16 * w + 4 * g + j;
      float val = acc[ct][j] + bias;
      float ge = 0.5f * val * (1.0f + erff(val * 0.70710678118654752f));
      h1[(size_t)mrow * 512 + colbase + col] = f2bf(ge);
    }
  }
}

// Kernel F: MLP2 + bias + residual(x) -> out fp32
__global__ __launch_bounds__(512, 4) void mlp2_kernel(
    const short* __restrict__ h1, const short* __restrict__ w2,
    const float* __restrict__ mb2, const float* __restrict__ x,
    float* __restrict__ out) {
  floatx4 acc[16];
  gemm_core<512>(h1 + (size_t)blockIdx.x * 128 * 512, w2, acc);
  const int tid = threadIdx.x, w = tid >> 6, l = tid & 63, lr = l & 15, g = l >> 4;
#pragma unroll
  for (int ct = 0; ct < 16; ++ct) {
    int col = ct * 16 + lr;
    float bias = mb2[col];
#pragma unroll
    for (int j = 0; j < 4; ++j) {
      int mrow = blockIdx.x * 128 + 16 * w + 4 * g + j;
      out[(size_t)mrow * 256 + col] = x[(size_t)mrow * 256 + col] + acc[ct][j] + bias;
    }
  }
}

// ---------------------------------------------------------------------------
extern "C" void kernel_launch(void* const* d_in, const int* in_sizes, int n_in,
                              void* d_out, int out_size, void* d_ws, size_t ws_size,
                              hipStream_t stream) {
  const float* q = (const float*)d_in[0];
  const float* k = (const float*)d_in[1];
  const float* v = (const float*)d_in[2];
  const float* gq = (const float*)d_in[3];
  const float* bq = (const float*)d_in[4];
  const float* gk = (const float*)d_in[5];
  const float* bk = (const float*)d_in[6];
  const float* gv = (const float*)d_in[7];
  const float* bv = (const float*)d_in[8];
  const float* bias_table = (const float*)d_in[9];
  const float* proj_w = (const float*)d_in[10];
  const float* proj_b = (const float*)d_in[11];
  const float* g2 = (const float*)d_in[12];
  const float* b2 = (const float*)d_in[13];
  const float* mw1 = (const float*)d_in[14];
  const float* mb1 = (const float*)d_in[15];
  const float* mw2 = (const float*)d_in[16];
  const float* mb2 = (const float*)d_in[17];

  char* ws = (char*)d_ws;
  float2* sq = (float2*)(ws + 0);
  float2* sk = (float2*)(ws + 524288);
  float2* sv = (float2*)(ws + 1048576);
  float* x = (float*)(ws + 0);  // overwrites stats only after attn is done
  short* ao = (short*)(ws + 67108864);
  short* h1 = (short*)(ws + 67108864);  // overlays ao (dead after proj)
  short* xln = (short*)(ws + 134217728);
  short* wp = (short*)(ws + 167772160);
  short* w1 = (short*)(ws + 167903232);
  short* w2 = (short*)(ws + 168165376);
  short* biasPb = (short*)(ws + 168427520);
  // ws requirement: 168,689,664 bytes

  // prep
  cvt_kernel<<<256, 256, 0, stream>>>(proj_w, wp, 65536);
  cvt_kernel<<<512, 256, 0, stream>>>(mw1, w1, 131072);
  cvt_kernel<<<512, 256, 0, stream>>>(mw2, w2, 131072);
  biasprep_kernel<<<512, 256, 0, stream>>>(bias_table, biasPb);

  // S: LN stats for q,k,v
  stats_kernel<<<dim3(16384, 3), 256, 0, stream>>>(q, k, v, sq, sk, sv);

  // B: attention
  attn_kernel<<<dim3(512, 8), 256, 0, stream>>>(q, k, v, gq, bq, gk, bk, gv, bv,
                                                sq, sk, sv, biasPb, ao);

  // C: proj + residual + fused LN2
  proj_kernel<<<512, 512, 0, stream>>>(ao, wp, proj_b, v, g2, b2, x, xln);

  // E: MLP1 + GELU
  mlp1_kernel<<<dim3(512, 2), 512, 0, stream>>>(xln, w1, mb1, h1);

  // F: MLP2 + residual -> out
  mlp2_kernel<<<512, 512, 0, stream>>>(h1, w2, mb2, x, (float*)d_out);
}

// Round 3
// 236.842 us; speedup vs baseline: 1.1648x; 1.0534x over previous
//
#include <hip/hip_runtime.h>
#include <math.h>

// ---------------------------------------------------------------------------
// Round 3: structural fusion — no x/xln/h1 HBM round-trips.
//   prep:  proj_w/mw1/mw2 fp32->bf16 ; bias_table -> biasPb[h][n][lr][8] bf16
//   A: ln_qkv: LN(q,k,v) + window partition -> qw/kw/vw bf16 [512][128][256]
//   B: attn per (window,head), 40KB LDS, swizzled Ps/Vt, bf16 bias -> ao
//   X: xpath per 64-row tile (1024 blocks, 256 thr, 80KB LDS):
//      proj GEMM -> +bias +residual(v) + LN2 (registers/shfl) -> xln LDS
//      -> 4x [MLP1 quarter GEMM + GELU -> h1q LDS -> MLP2 partial GEMM]
//      -> out = x + mlp2 + bias   (x kept in VGPRs the whole time)
//
// Workspace layout (bytes):
//   qw   [0,          33554432)
//   kw   [33554432,   67108864)
//   vw   [67108864,  100663296)
//   ao   [100663296, 134217728)
//   wp   [167772160, 167903232)
//   w1   [167903232, 168165376)
//   w2   [168165376, 168427520)
//   biasPb [168427520, 168689664)
// ---------------------------------------------------------------------------

typedef __attribute__((ext_vector_type(8))) short short8;
typedef __attribute__((ext_vector_type(4))) short shortx4;
typedef __attribute__((ext_vector_type(4))) float floatx4;

#define MFMA16(a, b, c) __builtin_amdgcn_mfma_f32_16x16x32_bf16((a), (b), (c), 0, 0, 0)
#define ATT_SCALE 0.17677669529663689f /* 32^-0.5 */

__device__ __forceinline__ short f2bf(float f) {
  unsigned u = __float_as_uint(f);
  u += 0x7fffu + ((u >> 16) & 1u);
  return (short)(u >> 16);
}
__device__ __forceinline__ float bf2f(short s) {
  return __uint_as_float(((unsigned)(unsigned short)s) << 16);
}
__device__ __forceinline__ void gl2lds(const short* g, short* l) {
  __builtin_amdgcn_global_load_lds((const __attribute__((address_space(1))) void*)(g),
                                   (__attribute__((address_space(3))) void*)(l), 16, 0, 0);
}

// ---------------------------------------------------------------------------
// prep kernels
// ---------------------------------------------------------------------------
__global__ void cvt_kernel(const float* __restrict__ src, short* __restrict__ dst, int n) {
  int i = blockIdx.x * 256 + threadIdx.x;
  if (i < n) dst[i] = f2bf(src[i]);
}

__global__ void biasprep_kernel(const float* __restrict__ table, short* __restrict__ biasPb) {
  int idx = blockIdx.x * 256 + threadIdx.x;  // [0, 131072)
  int h = idx >> 14;
  int n = (idx >> 7) & 127;
  int lr = (idx >> 3) & 15;
  int c = idx & 7;
  int m = 16 * c + lr;
  int t1 = n >> 6, h1 = (n >> 3) & 7, w1 = n & 7;
  int t2 = m >> 6, h2 = (m >> 3) & 7, w2 = m & 7;
  int ridx = (t1 - t2 + 1) * 225 + (h1 - h2 + 7) * 15 + (w1 - w2 + 7);
  biasPb[idx] = f2bf(table[ridx * 8 + h]);
}

// ---------------------------------------------------------------------------
// Kernel A: LN + window partition, fp32 -> bf16 window layout. One wave/token.
// ---------------------------------------------------------------------------
__global__ __launch_bounds__(256) void ln_qkv_kernel(
    const float* __restrict__ q, const float* __restrict__ k, const float* __restrict__ v,
    const float* __restrict__ gq, const float* __restrict__ bq,
    const float* __restrict__ gk, const float* __restrict__ bk,
    const float* __restrict__ gv, const float* __restrict__ bv,
    short* __restrict__ qw, short* __restrict__ kw, short* __restrict__ vw) {
  const int wv = threadIdx.x >> 6, l = threadIdx.x & 63;
  const int tok = blockIdx.x * 4 + wv;
  const int which = blockIdx.y;
  const float* src = (which == 0) ? q : ((which == 1) ? k : v);
  const float* gg  = (which == 0) ? gq : ((which == 1) ? gk : gv);
  const float* bb  = (which == 0) ? bq : ((which == 1) ? bk : bv);
  short* dst       = (which == 0) ? qw : ((which == 1) ? kw : vw);

  float4 xv = *(const float4*)(src + (size_t)tok * 256 + l * 4);
  float s1 = xv.x + xv.y + xv.z + xv.w;
  float s2 = xv.x * xv.x + xv.y * xv.y + xv.z * xv.z + xv.w * xv.w;
#pragma unroll
  for (int off = 1; off < 64; off <<= 1) {
    s1 += __shfl_xor(s1, off);
    s2 += __shfl_xor(s2, off);
  }
  float mean = s1 * (1.0f / 256.0f);
  float var = s2 * (1.0f / 256.0f) - mean * mean;
  float inv = rsqrtf(var + 1e-5f);

  int b_ = tok >> 15, rem = tok & 32767;
  int t = rem >> 12, hh = (rem >> 6) & 63, ww = rem & 63;
  int wi = ((b_ * 4 + (t >> 1)) * 8 + (hh >> 3)) * 8 + (ww >> 3);
  int n = ((t & 1) << 6) | ((hh & 7) << 3) | (ww & 7);

  float4 g4 = *(const float4*)(gg + l * 4);
  float4 b4 = *(const float4*)(bb + l * 4);
  shortx4 o;
  o[0] = f2bf((xv.x - mean) * inv * g4.x + b4.x);
  o[1] = f2bf((xv.y - mean) * inv * g4.y + b4.y);
  o[2] = f2bf((xv.z - mean) * inv * g4.z + b4.z);
  o[3] = f2bf((xv.w - mean) * inv * g4.w + b4.w);
  *(shortx4*)(dst + ((size_t)wi * 128 + n) * 256 + l * 4) = o;
}

// ---------------------------------------------------------------------------
// Kernel B: windowed attention, one block per (window, head), 4 waves, 40KB LDS.
// ---------------------------------------------------------------------------
__global__ __launch_bounds__(256, 4) void attn_kernel(
    const short* __restrict__ qw, const short* __restrict__ kw, const short* __restrict__ vw,
    const short* __restrict__ biasPb, short* __restrict__ ao) {
  __shared__ union SU {
    struct { short Qs[128][40]; short Ks[128][40]; } qk;
    short Ps[128 * 128];  // XOR-swizzled
  } su;
  __shared__ short Vt[32 * 128];  // V^T, XOR-swizzled

  const int wi = blockIdx.x, h = blockIdx.y, tid = threadIdx.x;
  const size_t base = (size_t)wi * 128 * 256 + h * 32;

#pragma unroll
  for (int i = 0; i < 2; ++i) {
    int idx = tid + 256 * i;        // 0..511
    int m = idx >> 2, c = idx & 3;  // token row, 8-elem unit
    *(short8*)&su.qk.Qs[m][c * 8] = *(const short8*)(qw + base + (size_t)m * 256 + c * 8);
    *(short8*)&su.qk.Ks[m][c * 8] = *(const short8*)(kw + base + (size_t)m * 256 + c * 8);
    short8 vv = *(const short8*)(vw + base + (size_t)m * 256 + c * 8);
#pragma unroll
    for (int e = 0; e < 8; ++e) {
      int d = c * 8 + e;
      Vt[d * 128 + (((m >> 3) ^ (d & 7)) << 3) + (m & 7)] = vv[e];
    }
  }
  __syncthreads();

  const int wvv = tid >> 6, l = tid & 63, lr = l & 15, g = l >> 4;
  const floatx4 zf = {0.f, 0.f, 0.f, 0.f};

  short8 aq0 = *(const short8*)&su.qk.Qs[32 * wvv + lr][g * 8];
  short8 aq1 = *(const short8*)&su.qk.Qs[32 * wvv + 16 + lr][g * 8];

  floatx4 s[2][8];
#pragma unroll
  for (int c = 0; c < 8; ++c) {
    short8 bk8 = *(const short8*)&su.qk.Ks[16 * c + lr][g * 8];
    s[0][c] = MFMA16(aq0, bk8, zf);
    s[1][c] = MFMA16(aq1, bk8, zf);
  }
  __syncthreads();  // Qs/Ks dead -> Ps region reusable

  const int lr7 = lr & 7;
#pragma unroll
  for (int r = 0; r < 2; ++r) {
#pragma unroll
    for (int j = 0; j < 4; ++j) {
      int n = 32 * wvv + 16 * r + 4 * g + j;
      short8 bv8 = *(const short8*)(biasPb + ((size_t)(h * 128 + n) * 16 + lr) * 8);
      float mx = -1e30f;
#pragma unroll
      for (int c = 0; c < 8; ++c) {
        float val = s[r][c][j] * ATT_SCALE + bf2f(bv8[c]);
        s[r][c][j] = val;
        mx = fmaxf(mx, val);
      }
#pragma unroll
      for (int off = 1; off < 16; off <<= 1) mx = fmaxf(mx, __shfl_xor(mx, off));
      float sum = 0.f;
#pragma unroll
      for (int c = 0; c < 8; ++c) {
        float e = __expf(s[r][c][j] - mx);
        s[r][c][j] = e;
        sum += e;
      }
#pragma unroll
      for (int off = 1; off < 16; off <<= 1) sum += __shfl_xor(sum, off);
      float invs = 1.0f / sum;
      int n7 = n & 7;
#pragma unroll
      for (int c = 0; c < 8; ++c) {
        int col = 16 * c + lr;
        su.Ps[n * 128 + (((col >> 3) ^ n7) << 3) + (col & 7)] = f2bf(s[r][c][j] * invs);
      }
    }
  }
  // each wave reads only its own 32 P rows below -> no barrier

  floatx4 o00 = zf, o01 = zf, o10 = zf, o11 = zf;
  const int ra0 = 32 * wvv + lr, ra1 = ra0 + 16;
#pragma unroll
  for (int ks = 0; ks < 4; ++ks) {
    int ulog = ks * 4 + g;
    short8 pa0 = *(const short8*)&su.Ps[ra0 * 128 + ((ulog ^ (ra0 & 7)) << 3)];
    short8 pa1 = *(const short8*)&su.Ps[ra1 * 128 + ((ulog ^ (ra1 & 7)) << 3)];
    short8 vb0 = *(const short8*)&Vt[lr * 128 + ((ulog ^ lr7) << 3)];
    short8 vb1 = *(const short8*)&Vt[(16 + lr) * 128 + ((ulog ^ lr7) << 3)];
    o00 = MFMA16(pa0, vb0, o00);
    o01 = MFMA16(pa0, vb1, o01);
    o10 = MFMA16(pa1, vb0, o10);
    o11 = MFMA16(pa1, vb1, o11);
  }
#pragma unroll
  for (int j = 0; j < 4; ++j) {
    int n0 = 32 * wvv + 4 * g + j;
    int n1 = n0 + 16;
    size_t rb0 = ((size_t)wi * 128 + n0) * 256 + h * 32;
    size_t rb1 = ((size_t)wi * 128 + n1) * 256 + h * 32;
    ao[rb0 + lr] = f2bf(o00[j]);
    ao[rb0 + 16 + lr] = f2bf(o01[j]);
    ao[rb1 + lr] = f2bf(o10[j]);
    ao[rb1 + 16 + lr] = f2bf(o11[j]);
  }
}

// ---------------------------------------------------------------------------
// Kernel X: fused x-path. One block per 64 window-ordered rows. 256 thr, 4 waves.
// LDS: Ws 32KB | XL 32KB | H1 16KB (As overlays H1) = 80KB -> 2 blocks/CU.
// Each wave owns rows 16w..16w+15; acc tiles are 16 rows x N cols.
// ---------------------------------------------------------------------------
__global__ __launch_bounds__(256, 2) void xpath_kernel(
    const short* __restrict__ ao, const short* __restrict__ wp,
    const float* __restrict__ proj_b, const float* __restrict__ vin,
    const float* __restrict__ g2, const float* __restrict__ b2,
    const short* __restrict__ w1, const float* __restrict__ mb1,
    const short* __restrict__ w2, const float* __restrict__ mb2,
    float* __restrict__ out) {
  __shared__ short Ws[256 * 64];  // 32 KB weight staging (all GEMMs)
  __shared__ short XL[64 * 256];  // 32 KB xln tile, XOR-swizzled
  __shared__ short H1[64 * 128];  // 16 KB h1 quarter, XOR-swizzled; As overlay
  short* As = H1;

  const int tid = threadIdx.x;
  const int w = tid >> 6, l = tid & 63, lr = l & 15, g = l >> 4;
  const int li = l >> 3, u = l & 7;
  const int swz = ((u ^ li) << 3);
  const int s0 = ((g ^ (lr & 7)) << 3);
  const int s1 = (((4 + g) ^ (lr & 7)) << 3);
  const floatx4 zf = {0.f, 0.f, 0.f, 0.f};
  const int bx = blockIdx.x;
  const int r16 = 16 * w + lr;  // A-frag row (local)

  // ---- P1: proj GEMM: acc1 = ao_tile[64x256] @ wp[256x256]^T ----
  floatx4 acc1[16];
#pragma unroll
  for (int i = 0; i < 16; ++i) acc1[i] = zf;
  const short* A = ao + (size_t)bx * 64 * 256;
  for (int k0 = 0; k0 < 256; k0 += 64) {
    if (k0) __syncthreads();
#pragma unroll
    for (int c = 0; c < 2; ++c)
      gl2lds(A + (size_t)((w + 4 * c) * 8 + li) * 256 + k0 + swz, As + (w + 4 * c) * 512);
#pragma unroll
    for (int c = 0; c < 8; ++c)
      gl2lds(wp + (size_t)((w + 4 * c) * 8 + li) * 256 + k0 + swz, Ws + (w + 4 * c) * 512);
    __syncthreads();
    short8 a0 = *(const short8*)&As[r16 * 64 + s0];
    short8 a1 = *(const short8*)&As[r16 * 64 + s1];
#pragma unroll
    for (int ct = 0; ct < 16; ++ct) {
      int rb = ct * 16 + lr;
      short8 b0 = *(const short8*)&Ws[rb * 64 + s0];
      acc1[ct] = MFMA16(a0, b0, acc1[ct]);
      short8 b1 = *(const short8*)&Ws[rb * 64 + s1];
      acc1[ct] = MFMA16(a1, b1, acc1[ct]);
    }
  }

  // ---- epilogue: x = acc1 + proj_b + v(residual); LN2 -> XL (bf16) ----
  int sidx4[4];
  float xr[16][4];
  {
    const int wiw = bx >> 1;
    const int wb = wiw & 7, hb = (wiw >> 3) & 7, tt = (wiw >> 6) & 3, b_ = wiw >> 8;
#pragma unroll
    for (int j = 0; j < 4; ++j) {
      int row = 16 * w + 4 * g + j;          // local row 0..63
      int n = ((bx & 1) << 6) | row;         // pos in window 0..127
      int t = tt * 2 + (n >> 6), hh = hb * 8 + ((n >> 3) & 7), ww2 = wb * 8 + (n & 7);
      int sidx = ((b_ * 8 + t) * 64 + hh) * 64 + ww2;
      sidx4[j] = sidx;
      float ss1 = 0.f, ss2 = 0.f;
#pragma unroll
      for (int ct = 0; ct < 16; ++ct) {
        int col = ct * 16 + lr;
        float val = acc1[ct][j] + proj_b[col] + vin[(size_t)sidx * 256 + col];
        xr[ct][j] = val;
        ss1 += val;
        ss2 += val * val;
      }
#pragma unroll
      for (int off = 1; off < 16; off <<= 1) {
        ss1 += __shfl_xor(ss1, off);
        ss2 += __shfl_xor(ss2, off);
      }
      float mean = ss1 * (1.0f / 256.0f);
      float var = ss2 * (1.0f / 256.0f) - mean * mean;
      float inv = rsqrtf(var + 1e-5f);
      int r7 = row & 7;
#pragma unroll
      for (int ct = 0; ct < 16; ++ct) {
        int col = ct * 16 + lr;
        float xl = (xr[ct][j] - mean) * inv * g2[col] + b2[col];
        int uu = col >> 3;
        XL[row * 256 + (((uu & 24) | ((uu & 7) ^ r7)) << 3) + (col & 7)] = f2bf(xl);
      }
    }
  }
  __syncthreads();  // XL visible; all As(H1) reads retired

  // ---- P2: 4 quarters of MLP1 (GELU) feeding MLP2 partial sums ----
  floatx4 acc3[16];
#pragma unroll
  for (int i = 0; i < 16; ++i) acc3[i] = zf;

  for (int qt = 0; qt < 4; ++qt) {
    // GEMM2: h1q[64x128] = XL[64x256] @ w1[qt*128..+128][256]^T
    floatx4 acc2[8];
#pragma unroll
    for (int i = 0; i < 8; ++i) acc2[i] = zf;
    for (int k0 = 0; k0 < 256; k0 += 64) {
      __syncthreads();
#pragma unroll
      for (int c = 0; c < 4; ++c)
        gl2lds(w1 + (size_t)(qt * 128 + (w + 4 * c) * 8 + li) * 256 + k0 + swz,
               Ws + (w + 4 * c) * 512);
      __syncthreads();
      short8 a0 = *(const short8*)&XL[r16 * 256 + k0 + ((g ^ (r16 & 7)) << 3)];
      short8 a1 = *(const short8*)&XL[r16 * 256 + k0 + (((4 + g) ^ (r16 & 7)) << 3)];
#pragma unroll
      for (int ct = 0; ct < 8; ++ct) {
        int rb = ct * 16 + lr;
        short8 b0 = *(const short8*)&Ws[rb * 64 + s0];
        acc2[ct] = MFMA16(a0, b0, acc2[ct]);
        short8 b1 = *(const short8*)&Ws[rb * 64 + s1];
        acc2[ct] = MFMA16(a1, b1, acc2[ct]);
      }
    }
    // GELU -> H1 (bf16, swizzled). H1 reads of previous qt completed (barriers above).
#pragma unroll
    for (int ct = 0; ct < 8; ++ct) {
      int col = ct * 16 + lr;
      float bias = mb1[qt * 128 + col];
#pragma unroll
      for (int j = 0; j < 4; ++j) {
        int row = 16 * w + 4 * g + j;
        float val = acc2[ct][j] + bias;
        float ge = 0.5f * val * (1.0f + erff(val * 0.70710678118654752f));
        int uu = col >> 3;
        H1[row * 128 + (((uu & 8) | ((uu & 7) ^ (row & 7))) << 3) + (col & 7)] = f2bf(ge);
      }
    }
    // GEMM3 partial: acc3 += H1[64x128] @ w2[256][qt*128..+128]^T
    for (int k0 = 0; k0 < 128; k0 += 64) {
      __syncthreads();  // H1 writes visible (first iter); Ws reads of prev step done
#pragma unroll
      for (int c = 0; c < 8; ++c)
        gl2lds(w2 + (size_t)((w + 4 * c) * 8 + li) * 512 + qt * 128 + k0 + swz,
               Ws + (w + 4 * c) * 512);
      __syncthreads();
      short8 a0 = *(const short8*)&H1[r16 * 128 + k0 + ((g ^ (r16 & 7)) << 3)];
      short8 a1 = *(const short8*)&H1[r16 * 128 + k0 + (((4 + g) ^ (r16 & 7)) << 3)];
#pragma unroll
      for (int ct = 0; ct < 16; ++ct) {
        int rb = ct * 16 + lr;
        short8 b0 = *(const short8*)&Ws[rb * 64 + s0];
        acc3[ct] = MFMA16(a0, b0, acc3[ct]);
        short8 b1 = *(const short8*)&Ws[rb * 64 + s1];
        acc3[ct] = MFMA16(a1, b1, acc3[ct]);
      }
    }
  }

  // ---- final: out = x + mlp2 + mb2 (spatial scatter) ----
#pragma unroll
  for (int ct = 0; ct < 16; ++ct) {
    int col = ct * 16 + lr;
    float bias = mb2[col];
#pragma unroll
    for (int j = 0; j < 4; ++j)
      out[(size_t)sidx4[j] * 256 + col] = xr[ct][j] + acc3[ct][j] + bias;
  }
}

// ---------------------------------------------------------------------------
extern "C" void kernel_launch(void* const* d_in, const int* in_sizes, int n_in,
                              void* d_out, int out_size, void* d_ws, size_t ws_size,
                              hipStream_t stream) {
  const float* q = (const float*)d_in[0];
  const float* k = (const float*)d_in[1];
  const float* v = (const float*)d_in[2];
  const float* gq = (const float*)d_in[3];
  const float* bq = (const float*)d_in[4];
  const float* gk = (const float*)d_in[5];
  const float* bk = (const float*)d_in[6];
  const float* gv = (const float*)d_in[7];
  const float* bv = (const float*)d_in[8];
  const float* bias_table = (const float*)d_in[9];
  const float* proj_w = (const float*)d_in[10];
  const float* proj_b = (const float*)d_in[11];
  const float* g2 = (const float*)d_in[12];
  const float* b2 = (const float*)d_in[13];
  const float* mw1 = (const float*)d_in[14];
  const float* mb1 = (const float*)d_in[15];
  const float* mw2 = (const float*)d_in[16];
  const float* mb2 = (const float*)d_in[17];

  char* ws = (char*)d_ws;
  short* qw = (short*)(ws + 0);
  short* kw = (short*)(ws + 33554432);
  short* vw = (short*)(ws + 67108864);
  short* ao = (short*)(ws + 100663296);
  short* wp = (short*)(ws + 167772160);
  short* w1 = (short*)(ws + 167903232);
  short* w2 = (short*)(ws + 168165376);
  short* biasPb = (short*)(ws + 168427520);

  cvt_kernel<<<256, 256, 0, stream>>>(proj_w, wp, 65536);
  cvt_kernel<<<512, 256, 0, stream>>>(mw1, w1, 131072);
  cvt_kernel<<<512, 256, 0, stream>>>(mw2, w2, 131072);
  biasprep_kernel<<<512, 256, 0, stream>>>(bias_table, biasPb);

  ln_qkv_kernel<<<dim3(16384, 3), 256, 0, stream>>>(q, k, v, gq, bq, gk, bk, gv, bv, qw, kw, vw);

  attn_kernel<<<dim3(512, 8), 256, 0, stream>>>(qw, kw, vw, biasPb, ao);

  xpath_kernel<<<1024, 256, 0, stream>>>(ao, wp, proj_b, v, g2, b2, w1, mb1, w2, mb2,
                                         (float*)d_out);
}

// Round 4
// 225.800 us; speedup vs baseline: 1.2217x; 1.0489x over previous
//
#include <hip/hip_runtime.h>
#include <math.h>

// ---------------------------------------------------------------------------
// Round 4: xpath restructured for latency hiding.
//   prep:  proj_w/mw1/mw2 fp32->bf16 ; bias_table -> biasPb[h][n][lr][8] bf16
//   A: ln_qkv: LN(q,k,v) + window partition -> qw/kw/vw bf16 [512][128][256]
//   B: attn per (window,head), 40KB LDS, swizzled Ps/Vt, bf16 bias -> ao
//   X: xpath per WINDOW (512 blocks, 512 thr = 8 waves, 128KB LDS):
//      proj GEMM (A-frags direct from global; W staged once per k-step for
//      8 waves) -> +bias +residual(v) + LN2 (regs/shfl) -> XL (LDS, per-wave)
//      -> 4x [MLP1 quarter + GELU -> H1 (LDS, per-wave) -> MLP2 partial]
//      -> out = x + mlp2 + bias.  Only barriers: weight-staging pairs.
//
// Workspace layout unchanged from R3.
// ---------------------------------------------------------------------------

typedef __attribute__((ext_vector_type(8))) short short8;
typedef __attribute__((ext_vector_type(4))) short shortx4;
typedef __attribute__((ext_vector_type(4))) float floatx4;

#define MFMA16(a, b, c) __builtin_amdgcn_mfma_f32_16x16x32_bf16((a), (b), (c), 0, 0, 0)
#define ATT_SCALE 0.17677669529663689f /* 32^-0.5 */

__device__ __forceinline__ short f2bf(float f) {
  unsigned u = __float_as_uint(f);
  u += 0x7fffu + ((u >> 16) & 1u);
  return (short)(u >> 16);
}
__device__ __forceinline__ float bf2f(short s) {
  return __uint_as_float(((unsigned)(unsigned short)s) << 16);
}
__device__ __forceinline__ void gl2lds(const short* g, short* l) {
  __builtin_amdgcn_global_load_lds((const __attribute__((address_space(1))) void*)(g),
                                   (__attribute__((address_space(3))) void*)(l), 16, 0, 0);
}

// ---------------------------------------------------------------------------
// prep kernels
// ---------------------------------------------------------------------------
__global__ void cvt_kernel(const float* __restrict__ src, short* __restrict__ dst, int n) {
  int i = blockIdx.x * 256 + threadIdx.x;
  if (i < n) dst[i] = f2bf(src[i]);
}

__global__ void biasprep_kernel(const float* __restrict__ table, short* __restrict__ biasPb) {
  int idx = blockIdx.x * 256 + threadIdx.x;  // [0, 131072)
  int h = idx >> 14;
  int n = (idx >> 7) & 127;
  int lr = (idx >> 3) & 15;
  int c = idx & 7;
  int m = 16 * c + lr;
  int t1 = n >> 6, h1 = (n >> 3) & 7, w1 = n & 7;
  int t2 = m >> 6, h2 = (m >> 3) & 7, w2 = m & 7;
  int ridx = (t1 - t2 + 1) * 225 + (h1 - h2 + 7) * 15 + (w1 - w2 + 7);
  biasPb[idx] = f2bf(table[ridx * 8 + h]);
}

// ---------------------------------------------------------------------------
// Kernel A: LN + window partition, fp32 -> bf16 window layout. One wave/token.
// ---------------------------------------------------------------------------
__global__ __launch_bounds__(256) void ln_qkv_kernel(
    const float* __restrict__ q, const float* __restrict__ k, const float* __restrict__ v,
    const float* __restrict__ gq, const float* __restrict__ bq,
    const float* __restrict__ gk, const float* __restrict__ bk,
    const float* __restrict__ gv, const float* __restrict__ bv,
    short* __restrict__ qw, short* __restrict__ kw, short* __restrict__ vw) {
  const int wv = threadIdx.x >> 6, l = threadIdx.x & 63;
  const int tok = blockIdx.x * 4 + wv;
  const int which = blockIdx.y;
  const float* src = (which == 0) ? q : ((which == 1) ? k : v);
  const float* gg  = (which == 0) ? gq : ((which == 1) ? gk : gv);
  const float* bb  = (which == 0) ? bq : ((which == 1) ? bk : bv);
  short* dst       = (which == 0) ? qw : ((which == 1) ? kw : vw);

  float4 xv = *(const float4*)(src + (size_t)tok * 256 + l * 4);
  float s1 = xv.x + xv.y + xv.z + xv.w;
  float s2 = xv.x * xv.x + xv.y * xv.y + xv.z * xv.z + xv.w * xv.w;
#pragma unroll
  for (int off = 1; off < 64; off <<= 1) {
    s1 += __shfl_xor(s1, off);
    s2 += __shfl_xor(s2, off);
  }
  float mean = s1 * (1.0f / 256.0f);
  float var = s2 * (1.0f / 256.0f) - mean * mean;
  float inv = rsqrtf(var + 1e-5f);

  int b_ = tok >> 15, rem = tok & 32767;
  int t = rem >> 12, hh = (rem >> 6) & 63, ww = rem & 63;
  int wi = ((b_ * 4 + (t >> 1)) * 8 + (hh >> 3)) * 8 + (ww >> 3);
  int n = ((t & 1) << 6) | ((hh & 7) << 3) | (ww & 7);

  float4 g4 = *(const float4*)(gg + l * 4);
  float4 b4 = *(const float4*)(bb + l * 4);
  shortx4 o;
  o[0] = f2bf((xv.x - mean) * inv * g4.x + b4.x);
  o[1] = f2bf((xv.y - mean) * inv * g4.y + b4.y);
  o[2] = f2bf((xv.z - mean) * inv * g4.z + b4.z);
  o[3] = f2bf((xv.w - mean) * inv * g4.w + b4.w);
  *(shortx4*)(dst + ((size_t)wi * 128 + n) * 256 + l * 4) = o;
}

// ---------------------------------------------------------------------------
// Kernel B: windowed attention, one block per (window, head), 4 waves, 40KB LDS.
// ---------------------------------------------------------------------------
__global__ __launch_bounds__(256, 4) void attn_kernel(
    const short* __restrict__ qw, const short* __restrict__ kw, const short* __restrict__ vw,
    const short* __restrict__ biasPb, short* __restrict__ ao) {
  __shared__ union SU {
    struct { short Qs[128][40]; short Ks[128][40]; } qk;
    short Ps[128 * 128];  // XOR-swizzled
  } su;
  __shared__ short Vt[32 * 128];  // V^T, XOR-swizzled

  const int wi = blockIdx.x, h = blockIdx.y, tid = threadIdx.x;
  const size_t base = (size_t)wi * 128 * 256 + h * 32;

#pragma unroll
  for (int i = 0; i < 2; ++i) {
    int idx = tid + 256 * i;        // 0..511
    int m = idx >> 2, c = idx & 3;  // token row, 8-elem unit
    *(short8*)&su.qk.Qs[m][c * 8] = *(const short8*)(qw + base + (size_t)m * 256 + c * 8);
    *(short8*)&su.qk.Ks[m][c * 8] = *(const short8*)(kw + base + (size_t)m * 256 + c * 8);
    short8 vv = *(const short8*)(vw + base + (size_t)m * 256 + c * 8);
#pragma unroll
    for (int e = 0; e < 8; ++e) {
      int d = c * 8 + e;
      Vt[d * 128 + (((m >> 3) ^ (d & 7)) << 3) + (m & 7)] = vv[e];
    }
  }
  __syncthreads();

  const int wvv = tid >> 6, l = tid & 63, lr = l & 15, g = l >> 4;
  const floatx4 zf = {0.f, 0.f, 0.f, 0.f};

  short8 aq0 = *(const short8*)&su.qk.Qs[32 * wvv + lr][g * 8];
  short8 aq1 = *(const short8*)&su.qk.Qs[32 * wvv + 16 + lr][g * 8];

  floatx4 s[2][8];
#pragma unroll
  for (int c = 0; c < 8; ++c) {
    short8 bk8 = *(const short8*)&su.qk.Ks[16 * c + lr][g * 8];
    s[0][c] = MFMA16(aq0, bk8, zf);
    s[1][c] = MFMA16(aq1, bk8, zf);
  }
  __syncthreads();  // Qs/Ks dead -> Ps region reusable

  const int lr7 = lr & 7;
#pragma unroll
  for (int r = 0; r < 2; ++r) {
#pragma unroll
    for (int j = 0; j < 4; ++j) {
      int n = 32 * wvv + 16 * r + 4 * g + j;
      short8 bv8 = *(const short8*)(biasPb + ((size_t)(h * 128 + n) * 16 + lr) * 8);
      float mx = -1e30f;
#pragma unroll
      for (int c = 0; c < 8; ++c) {
        float val = s[r][c][j] * ATT_SCALE + bf2f(bv8[c]);
        s[r][c][j] = val;
        mx = fmaxf(mx, val);
      }
#pragma unroll
      for (int off = 1; off < 16; off <<= 1) mx = fmaxf(mx, __shfl_xor(mx, off));
      float sum = 0.f;
#pragma unroll
      for (int c = 0; c < 8; ++c) {
        float e = __expf(s[r][c][j] - mx);
        s[r][c][j] = e;
        sum += e;
      }
#pragma unroll
      for (int off = 1; off < 16; off <<= 1) sum += __shfl_xor(sum, off);
      float invs = 1.0f / sum;
      int n7 = n & 7;
#pragma unroll
      for (int c = 0; c < 8; ++c) {
        int col = 16 * c + lr;
        su.Ps[n * 128 + (((col >> 3) ^ n7) << 3) + (col & 7)] = f2bf(s[r][c][j] * invs);
      }
    }
  }
  // each wave reads only its own 32 P rows below -> no barrier

  floatx4 o00 = zf, o01 = zf, o10 = zf, o11 = zf;
  const int ra0 = 32 * wvv + lr, ra1 = ra0 + 16;
#pragma unroll
  for (int ks = 0; ks < 4; ++ks) {
    int ulog = ks * 4 + g;
    short8 pa0 = *(const short8*)&su.Ps[ra0 * 128 + ((ulog ^ (ra0 & 7)) << 3)];
    short8 pa1 = *(const short8*)&su.Ps[ra1 * 128 + ((ulog ^ (ra1 & 7)) << 3)];
    short8 vb0 = *(const short8*)&Vt[lr * 128 + ((ulog ^ lr7) << 3)];
    short8 vb1 = *(const short8*)&Vt[(16 + lr) * 128 + ((ulog ^ lr7) << 3)];
    o00 = MFMA16(pa0, vb0, o00);
    o01 = MFMA16(pa0, vb1, o01);
    o10 = MFMA16(pa1, vb0, o10);
    o11 = MFMA16(pa1, vb1, o11);
  }
#pragma unroll
  for (int j = 0; j < 4; ++j) {
    int n0 = 32 * wvv + 4 * g + j;
    int n1 = n0 + 16;
    size_t rb0 = ((size_t)wi * 128 + n0) * 256 + h * 32;
    size_t rb1 = ((size_t)wi * 128 + n1) * 256 + h * 32;
    ao[rb0 + lr] = f2bf(o00[j]);
    ao[rb0 + 16 + lr] = f2bf(o01[j]);
    ao[rb1 + lr] = f2bf(o10[j]);
    ao[rb1 + 16 + lr] = f2bf(o11[j]);
  }
}

// ---------------------------------------------------------------------------
// Kernel X: fused x-path. One block per WINDOW (128 rows), 512 thr = 8 waves.
// LDS: Ws 32KB (weight k-slice, shared by 8 waves) | XL 64KB | H1 32KB = 128KB.
// XL/H1 are per-wave-private row ranges -> barriers only around Ws staging.
// Wave w owns local rows [16w, 16w+16); lane (lr,g); A-frag row r16 = 16w+lr.
// ---------------------------------------------------------------------------
__global__ __launch_bounds__(512, 1) void xpath_kernel(
    const short* __restrict__ ao, const short* __restrict__ wp,
    const float* __restrict__ proj_b, const float* __restrict__ vin,
    const float* __restrict__ g2, const float* __restrict__ b2,
    const short* __restrict__ w1, const float* __restrict__ mb1,
    const short* __restrict__ w2, const float* __restrict__ mb2,
    float* __restrict__ out) {
  __shared__ short Ws[256 * 64];   // 32 KB
  __shared__ short XL[128 * 256];  // 64 KB, XOR-swizzled
  __shared__ short H1[128 * 128];  // 32 KB, XOR-swizzled

  const int tid = threadIdx.x;
  const int w = tid >> 6, l = tid & 63, lr = l & 15, g = l >> 4;
  const int li = l >> 3, u = l & 7;
  const int swz = ((u ^ li) << 3);
  const int s0 = ((g ^ (lr & 7)) << 3);
  const int s1 = (((4 + g) ^ (lr & 7)) << 3);
  const floatx4 zf = {0.f, 0.f, 0.f, 0.f};
  const int bx = blockIdx.x;       // window index
  const int r16 = 16 * w + lr;     // local A-frag row
  const size_t grow = (size_t)bx * 128;

  // ---- P1: proj GEMM: acc1 = ao[128x256] @ wp[256x256]^T ----
  floatx4 acc1[16];
#pragma unroll
  for (int i = 0; i < 16; ++i) acc1[i] = zf;
  for (int k0 = 0; k0 < 256; k0 += 64) {
    // A-frags direct from global (issued before barriers -> overlap staging)
    short8 a0 = *(const short8*)(ao + (grow + r16) * 256 + k0 + g * 8);
    short8 a1 = *(const short8*)(ao + (grow + r16) * 256 + k0 + 32 + g * 8);
    __syncthreads();  // prior k-step's Ws reads retired
#pragma unroll
    for (int i = 0; i < 4; ++i) {
      int c = w + 8 * i;
      gl2lds(wp + (size_t)(8 * c + li) * 256 + k0 + swz, Ws + c * 512);
    }
    __syncthreads();  // staged Ws visible
#pragma unroll
    for (int ct = 0; ct < 16; ++ct) {
      int rb = ct * 16 + lr;
      short8 b0 = *(const short8*)&Ws[rb * 64 + s0];
      acc1[ct] = MFMA16(a0, b0, acc1[ct]);
      short8 b1 = *(const short8*)&Ws[rb * 64 + s1];
      acc1[ct] = MFMA16(a1, b1, acc1[ct]);
    }
  }

  // ---- epilogue: x = acc1 + proj_b + v(residual); LN2 -> XL (bf16) ----
  int sidx4[4];
  float xr[16][4];
  {
    const int wb = bx & 7, hb = (bx >> 3) & 7, tt = (bx >> 6) & 3, b_ = bx >> 8;
#pragma unroll
    for (int j = 0; j < 4; ++j) {
      int row = 16 * w + 4 * g + j;  // local row == pos in window (0..127)
      int t = tt * 2 + (row >> 6), hh = hb * 8 + ((row >> 3) & 7), ww2 = wb * 8 + (row & 7);
      int sidx = ((b_ * 8 + t) * 64 + hh) * 64 + ww2;
      sidx4[j] = sidx;
      float ss1 = 0.f, ss2 = 0.f;
#pragma unroll
      for (int ct = 0; ct < 16; ++ct) {
        int col = ct * 16 + lr;
        float val = acc1[ct][j] + proj_b[col] + vin[(size_t)sidx * 256 + col];
        xr[ct][j] = val;
        ss1 += val;
        ss2 += val * val;
      }
#pragma unroll
      for (int off = 1; off < 16; off <<= 1) {
        ss1 += __shfl_xor(ss1, off);
        ss2 += __shfl_xor(ss2, off);
      }
      float mean = ss1 * (1.0f / 256.0f);
      float var = ss2 * (1.0f / 256.0f) - mean * mean;
      float inv = rsqrtf(var + 1e-5f);
      int r7 = row & 7;
#pragma unroll
      for (int ct = 0; ct < 16; ++ct) {
        int col = ct * 16 + lr;
        float xl = (xr[ct][j] - mean) * inv * g2[col] + b2[col];
        int uu = col >> 3;
        XL[row * 256 + (((uu & 24) | ((uu & 7) ^ r7)) << 3) + (col & 7)] = f2bf(xl);
      }
    }
  }
  // No barrier: each wave re-reads only its own XL rows; staging barriers below
  // provide the lgkmcnt drain before first read.

  // ---- P2: 4 quarters of MLP1 (GELU) feeding MLP2 partial sums ----
  floatx4 acc3[16];
#pragma unroll
  for (int i = 0; i < 16; ++i) acc3[i] = zf;

  for (int qt = 0; qt < 4; ++qt) {
    // MLP1 quarter: h1q[128x128] = XL[128x256] @ w1[qt*128..+128][256]^T
    floatx4 acc2[8];
#pragma unroll
    for (int i = 0; i < 8; ++i) acc2[i] = zf;
    for (int k0 = 0; k0 < 256; k0 += 64) {
      __syncthreads();  // prior Ws reads retired (also drains XL writes, qt=0)
#pragma unroll
      for (int i = 0; i < 2; ++i) {
        int c = w + 8 * i;
        gl2lds(w1 + (size_t)(qt * 128 + 8 * c + li) * 256 + k0 + swz, Ws + c * 512);
      }
      __syncthreads();
      short8 a0 = *(const short8*)&XL[r16 * 256 + k0 + ((g ^ (r16 & 7)) << 3)];
      short8 a1 = *(const short8*)&XL[r16 * 256 + k0 + (((4 + g) ^ (r16 & 7)) << 3)];
#pragma unroll
      for (int ct = 0; ct < 8; ++ct) {
        int rb = ct * 16 + lr;
        short8 b0 = *(const short8*)&Ws[rb * 64 + s0];
        acc2[ct] = MFMA16(a0, b0, acc2[ct]);
        short8 b1 = *(const short8*)&Ws[rb * 64 + s1];
        acc2[ct] = MFMA16(a1, b1, acc2[ct]);
      }
    }
    // GELU -> H1 (per-wave rows; next staging barrier drains before reads)
#pragma unroll
    for (int ct = 0; ct < 8; ++ct) {
      int col = ct * 16 + lr;
      float bias = mb1[qt * 128 + col];
#pragma unroll
      for (int j = 0; j < 4; ++j) {
        int row = 16 * w + 4 * g + j;
        float val = acc2[ct][j] + bias;
        float ge = 0.5f * val * (1.0f + erff(val * 0.70710678118654752f));
        int uu = col >> 3;
        H1[row * 128 + (((uu & 8) | ((uu & 7) ^ (row & 7))) << 3) + (col & 7)] = f2bf(ge);
      }
    }
    // MLP2 partial: acc3 += H1[128x128] @ w2[256][qt*128..+128]^T
    for (int k0 = 0; k0 < 128; k0 += 64) {
      __syncthreads();  // prior Ws reads retired; H1 writes drained
#pragma unroll
      for (int i = 0; i < 4; ++i) {
        int c = w + 8 * i;
        gl2lds(w2 + (size_t)(8 * c + li) * 512 + qt * 128 + k0 + swz, Ws + c * 512);
      }
      __syncthreads();
      short8 a0 = *(const short8*)&H1[r16 * 128 + k0 + ((g ^ (r16 & 7)) << 3)];
      short8 a1 = *(const short8*)&H1[r16 * 128 + k0 + (((4 + g) ^ (r16 & 7)) << 3)];
#pragma unroll
      for (int ct = 0; ct < 16; ++ct) {
        int rb = ct * 16 + lr;
        short8 b0 = *(const short8*)&Ws[rb * 64 + s0];
        acc3[ct] = MFMA16(a0, b0, acc3[ct]);
        short8 b1 = *(const short8*)&Ws[rb * 64 + s1];
        acc3[ct] = MFMA16(a1, b1, acc3[ct]);
      }
    }
  }

  // ---- final: out = x + mlp2 + mb2 (spatial scatter) ----
#pragma unroll
  for (int ct = 0; ct < 16; ++ct) {
    int col = ct * 16 + lr;
    float bias = mb2[col];
#pragma unroll
    for (int j = 0; j < 4; ++j)
      out[(size_t)sidx4[j] * 256 + col] = xr[ct][j] + acc3[ct][j] + bias;
  }
}

// ---------------------------------------------------------------------------
extern "C" void kernel_launch(void* const* d_in, const int* in_sizes, int n_in,
                              void* d_out, int out_size, void* d_ws, size_t ws_size,
                              hipStream_t stream) {
  const float* q = (const float*)d_in[0];
  const float* k = (const float*)d_in[1];
  const float* v = (const float*)d_in[2];
  const float* gq = (const float*)d_in[3];
  const float* bq = (const float*)d_in[4];
  const float* gk = (const float*)d_in[5];
  const float* bk = (const float*)d_in[6];
  const float* gv = (const float*)d_in[7];
  const float* bv = (const float*)d_in[8];
  const float* bias_table = (const float*)d_in[9];
  const float* proj_w = (const float*)d_in[10];
  const float* proj_b = (const float*)d_in[11];
  const float* g2 = (const float*)d_in[12];
  const float* b2 = (const float*)d_in[13];
  const float* mw1 = (const float*)d_in[14];
  const float* mb1 = (const float*)d_in[15];
  const float* mw2 = (const float*)d_in[16];
  const float* mb2 = (const float*)d_in[17];

  char* ws = (char*)d_ws;
  short* qw = (short*)(ws + 0);
  short* kw = (short*)(ws + 33554432);
  short* vw = (short*)(ws + 67108864);
  short* ao = (short*)(ws + 100663296);
  short* wp = (short*)(ws + 167772160);
  short* w1 = (short*)(ws + 167903232);
  short* w2 = (short*)(ws + 168165376);
  short* biasPb = (short*)(ws + 168427520);

  cvt_kernel<<<256, 256, 0, stream>>>(proj_w, wp, 65536);
  cvt_kernel<<<512, 256, 0, stream>>>(mw1, w1, 131072);
  cvt_kernel<<<512, 256, 0, stream>>>(mw2, w2, 131072);
  biasprep_kernel<<<512, 256, 0, stream>>>(bias_table, biasPb);

  ln_qkv_kernel<<<dim3(16384, 3), 256, 0, stream>>>(q, k, v, gq, bq, gk, bk, gv, bv, qw, kw, vw);

  attn_kernel<<<dim3(512, 8), 256, 0, stream>>>(qw, kw, vw, biasPb, ao);

  xpath_kernel<<<512, 512, 0, stream>>>(ao, wp, proj_b, v, g2, b2, w1, mb1, w2, mb2,
                                        (float*)d_out);
}